// Round 1
// baseline (1265.341 us; speedup 1.0000x reference)
//
#include <hip/hip_runtime.h>
#include <hip/hip_fp16.h>
#include <cmath>

// Problem constants (B=2, S=2048, D=1024, F=4096, E=8, TOP_K=2)
#define T_TOKENS 4096
#define DDIM     1024
#define FDIM     4096
#define NEXP     8
#define NPAIR    8192   // T_TOKENS * TOP_K

typedef _Float16 half8  __attribute__((ext_vector_type(8)));
typedef _Float16 half4v __attribute__((ext_vector_type(4)));
typedef float    floatx4 __attribute__((ext_vector_type(4)));

// ---------------- workspace layout ----------------
static const size_t OFF_XH  = 0;                                   // [T][D] f16
static const size_t SZ_XH   = (size_t)T_TOKENS * DDIM * 2;         // 8 MiB
static const size_t OFF_W1T = OFF_XH + SZ_XH;                      // [E][F][D] f16
static const size_t SZ_WT   = (size_t)NEXP * FDIM * DDIM * 2;      // 64 MiB
static const size_t OFF_W2T = OFF_W1T + SZ_WT;                     // [E][D][F] f16
static const size_t OFF_H   = OFF_W2T + SZ_WT;                     // [NPAIR][F] f16
static const size_t SZ_H    = (size_t)NPAIR * FDIM * 2;            // 64 MiB
static const size_t OFF_PT  = OFF_H + SZ_H;                        // pair_tok int
static const size_t OFF_PW  = OFF_PT + NPAIR * 4;                  // pair_w  f32
static const size_t OFF_TI  = OFF_PW + NPAIR * 4;                  // top_idx int [T][2]
static const size_t OFF_TW  = OFF_TI + NPAIR * 4;                  // top_w   f32 [T][2]
static const size_t OFF_CNT = OFF_TW + NPAIR * 4;                  // counts[8]
static const size_t OFF_OFS = OFF_CNT + 64;                        // offsets[9]
static const size_t OFF_CUR = OFF_OFS + 64;                        // cursors[8]
static const size_t WS_NEED = OFF_CUR + 64;

// ---------------- router: logits -> softmax -> top2; also emit x as f16 ----------------
__global__ __launch_bounds__(256)
void router_kernel(const float* __restrict__ x, const float* __restrict__ choice,
                   _Float16* __restrict__ xh, int* __restrict__ top_idx,
                   float* __restrict__ top_w, int* __restrict__ counts)
{
    __shared__ float ch[NEXP * DDIM];                 // 32 KiB
    for (int i = threadIdx.x * 4; i < NEXP * DDIM; i += 256 * 4) {
        *(float4*)&ch[i] = *(const float4*)&choice[i];
    }
    __syncthreads();

    const int lane = threadIdx.x & 63;
    const int wv   = threadIdx.x >> 6;
    const int t    = blockIdx.x * 4 + wv;             // one wave per token

    const float* xp = x + (size_t)t * DDIM;
    float4 xr[4];
#pragma unroll
    for (int p = 0; p < 4; ++p) xr[p] = *(const float4*)(xp + p * 256 + lane * 4);

    // emit f16 copy of x (coalesced 8B stores)
#pragma unroll
    for (int p = 0; p < 4; ++p) {
        half4v hv = { (_Float16)xr[p].x, (_Float16)xr[p].y,
                      (_Float16)xr[p].z, (_Float16)xr[p].w };
        *(half4v*)(xh + (size_t)t * DDIM + p * 256 + lane * 4) = hv;
    }

    float lg[NEXP];
#pragma unroll
    for (int e = 0; e < NEXP; ++e) {
        float s = 0.f;
#pragma unroll
        for (int p = 0; p < 4; ++p) {
            float4 c4 = *(float4*)&ch[e * DDIM + p * 256 + lane * 4];
            s += xr[p].x * c4.x + xr[p].y * c4.y + xr[p].z * c4.z + xr[p].w * c4.w;
        }
#pragma unroll
        for (int o = 32; o; o >>= 1) s += __shfl_xor(s, o, 64);
        lg[e] = s;
    }

    if (lane == 0) {
        float mx = lg[0];
#pragma unroll
        for (int e = 1; e < NEXP; ++e) mx = fmaxf(mx, lg[e]);
        float w[NEXP]; float sum = 0.f;
#pragma unroll
        for (int e = 0; e < NEXP; ++e) { w[e] = expf(lg[e] - mx); sum += w[e]; }
        float inv = 1.f / sum;
#pragma unroll
        for (int e = 0; e < NEXP; ++e) w[e] *= inv;
        // top-2, strict > so ties keep the lowest index (matches jax.lax.top_k)
        int i0 = 0; float w0 = w[0];
#pragma unroll
        for (int e = 1; e < NEXP; ++e) if (w[e] > w0) { w0 = w[e]; i0 = e; }
        int i1 = -1; float w1 = -1.f;
#pragma unroll
        for (int e = 0; e < NEXP; ++e) if (e != i0 && w[e] > w1) { w1 = w[e]; i1 = e; }
        top_idx[t * 2 + 0] = i0;  top_w[t * 2 + 0] = w0;
        top_idx[t * 2 + 1] = i1;  top_w[t * 2 + 1] = w1;
        atomicAdd(&counts[i0], 1);
        atomicAdd(&counts[i1], 1);
    }
}

__global__ void scan_kernel(const int* __restrict__ counts, int* __restrict__ offsets,
                            int* __restrict__ cursors)
{
    if (threadIdx.x == 0) {
        int o = 0;
        for (int e = 0; e < NEXP; ++e) { offsets[e] = o; cursors[e] = o; o += counts[e]; }
        offsets[NEXP] = o;
    }
}

__global__ __launch_bounds__(256)
void fill_kernel(const int* __restrict__ top_idx, const float* __restrict__ top_w,
                 int* __restrict__ cursors, int* __restrict__ pair_tok,
                 float* __restrict__ pair_w)
{
    int t = blockIdx.x * 256 + threadIdx.x;
#pragma unroll
    for (int k = 0; k < 2; ++k) {
        int e = top_idx[t * 2 + k];
        int pos = atomicAdd(&cursors[e], 1);
        pair_tok[pos] = t;
        pair_w[pos]   = top_w[t * 2 + k];
    }
}

// ---------------- transpose + f32->f16 convert: in [E][R][C] -> out [E][C][R] ----------------
__global__ __launch_bounds__(256)
void transpose_cvt(const float* __restrict__ in, _Float16* __restrict__ out, int R, int C)
{
    __shared__ float tile[64][65];
    const int e  = blockIdx.z;
    const float*    ip = in  + ((size_t)e * R + blockIdx.y * 64) * C + blockIdx.x * 64;
    _Float16*       op = out + ((size_t)e * C + blockIdx.x * 64) * R + blockIdx.y * 64;
    const int lr = threadIdx.x >> 4;          // 0..15
    const int lc = (threadIdx.x & 15) * 4;    // 0..60
#pragma unroll
    for (int p = 0; p < 4; ++p) {
        float4 v = *(const float4*)(ip + (size_t)(lr + p * 16) * C + lc);
        tile[lc + 0][lr + p * 16] = v.x;
        tile[lc + 1][lr + p * 16] = v.y;
        tile[lc + 2][lr + p * 16] = v.z;
        tile[lc + 3][lr + p * 16] = v.w;
    }
    __syncthreads();
#pragma unroll
    for (int p = 0; p < 4; ++p) {
        int oc = lr + p * 16;
        half4v hv = { (_Float16)tile[oc][lc + 0], (_Float16)tile[oc][lc + 1],
                      (_Float16)tile[oc][lc + 2], (_Float16)tile[oc][lc + 3] };
        *(half4v*)(op + (size_t)oc * R + lc) = hv;
    }
}

// ---------------- grouped GEMM: C[M,N] = A[M,K] * Bt[N,K]^T per expert ----------------
// GATHER: A rows via pair_tok (GEMM1, A=xh). else A row = pair index (GEMM2, A=H).
// EPI 0: silu -> Hout f16.   EPI 1: *pair_w -> atomicAdd into Yout (f32, token scatter).
template<bool GATHER, int EPI>
__global__ __launch_bounds__(256)
void moe_gemm(const _Float16* __restrict__ Abase, const _Float16* __restrict__ Bt,
              _Float16* __restrict__ Hout, float* __restrict__ Yout,
              const int* __restrict__ pair_tok, const float* __restrict__ pair_w,
              const int* __restrict__ counts, const int* __restrict__ offsets,
              const int K, const int N)
{
    const int e   = blockIdx.z;
    const int cnt = counts[e];
    const int mb  = blockIdx.y;
    if (mb * 128 >= cnt) return;
    const int off = offsets[e];

    const int tid  = threadIdx.x;
    const int lane = tid & 63;
    const int wv   = tid >> 6;
    const int wm   = wv >> 1, wn = wv & 1;

    __shared__ __align__(16) _Float16 As[128][40];   // +8 halves pad: conflict-floor
    __shared__ __align__(16) _Float16 Bs[128][40];

    // staging: each thread owns 2 rows (r, r+64) x one 16B chunk of BK=32
    const int srow = tid >> 2;       // 0..63
    const int schk = tid & 3;        // 16B chunk within 64B row

    const _Float16* arow[2];
#pragma unroll
    for (int h = 0; h < 2; ++h) {
        int pr = off + mb * 128 + srow + h * 64;
        if (pr > NPAIR - 1) pr = NPAIR - 1;
        long rowi = GATHER ? (long)pair_tok[pr] : (long)pr;
        arow[h] = Abase + (size_t)rowi * K;
    }
    const _Float16* brow[2];
#pragma unroll
    for (int h = 0; h < 2; ++h) {
        int n = blockIdx.x * 128 + srow + h * 64;
        brow[h] = Bt + ((size_t)e * N + n) * K;
    }

    floatx4 acc[4][4];
    floatx4 zero = {0.f, 0.f, 0.f, 0.f};
#pragma unroll
    for (int i = 0; i < 4; ++i)
#pragma unroll
        for (int j = 0; j < 4; ++j) acc[i][j] = zero;

    const int nK = K >> 5;
    uint4 ra[2], rb[2];
#pragma unroll
    for (int h = 0; h < 2; ++h) {
        ra[h] = *(const uint4*)(arow[h] + schk * 8);
        rb[h] = *(const uint4*)(brow[h] + schk * 8);
    }

    const int kc = (lane >> 4) * 8;  // K-chunk for MFMA fragments
    const int fr = lane & 15;

    for (int kt = 0; kt < nK; ++kt) {
        __syncthreads();
        *(uint4*)&As[srow     ][schk * 8] = ra[0];
        *(uint4*)&As[srow + 64][schk * 8] = ra[1];
        *(uint4*)&Bs[srow     ][schk * 8] = rb[0];
        *(uint4*)&Bs[srow + 64][schk * 8] = rb[1];
        __syncthreads();
        if (kt + 1 < nK) {
            const int ko = (kt + 1) * 32 + schk * 8;
            ra[0] = *(const uint4*)(arow[0] + ko);
            ra[1] = *(const uint4*)(arow[1] + ko);
            rb[0] = *(const uint4*)(brow[0] + ko);
            rb[1] = *(const uint4*)(brow[1] + ko);
        }
        half8 af[4], bf[4];
#pragma unroll
        for (int i = 0; i < 4; ++i) af[i] = *(const half8*)&As[wm * 64 + i * 16 + fr][kc];
#pragma unroll
        for (int j = 0; j < 4; ++j) bf[j] = *(const half8*)&Bs[wn * 64 + j * 16 + fr][kc];
#pragma unroll
        for (int i = 0; i < 4; ++i)
#pragma unroll
            for (int j = 0; j < 4; ++j)
                acc[i][j] = __builtin_amdgcn_mfma_f32_16x16x32_f16(af[i], bf[j], acc[i][j], 0, 0, 0);
    }

    // epilogue: C/D layout col = lane&15, row = (lane>>4)*4 + reg  [m89-verified]
    const int qr = lane >> 4;
    const int nbase = blockIdx.x * 128 + wn * 64;
#pragma unroll
    for (int i = 0; i < 4; ++i) {
#pragma unroll
        for (int r = 0; r < 4; ++r) {
            const int gm = mb * 128 + wm * 64 + i * 16 + qr * 4 + r;
            if (gm < cnt) {
                if (EPI == 0) {
                    const size_t hrow = (size_t)(off + gm) * FDIM;
#pragma unroll
                    for (int j = 0; j < 4; ++j) {
                        float v = acc[i][j][r];
                        v = v / (1.f + expf(-v));            // silu
                        Hout[hrow + nbase + j * 16 + fr] = (_Float16)v;
                    }
                } else {
                    const int pr = off + gm;
                    const int tok = pair_tok[pr];
                    const float w = pair_w[pr];
                    const size_t yrow = (size_t)tok * DDIM;
#pragma unroll
                    for (int j = 0; j < 4; ++j)
                        atomicAdd(&Yout[yrow + nbase + j * 16 + fr], w * acc[i][j][r]);
                }
            }
        }
    }
}

// ---------------- launch ----------------
extern "C" void kernel_launch(void* const* d_in, const int* in_sizes, int n_in,
                              void* d_out, int out_size, void* d_ws, size_t ws_size,
                              hipStream_t stream)
{
    const float* x      = (const float*)d_in[0];
    const float* choice = (const float*)d_in[1];
    const float* W1     = (const float*)d_in[2];
    const float* W2     = (const float*)d_in[3];
    float* y = (float*)d_out;

    char* ws = (char*)d_ws;
    if (ws_size < WS_NEED) return;   // need ~200 MiB of scratch

    _Float16* xh  = (_Float16*)(ws + OFF_XH);
    _Float16* W1T = (_Float16*)(ws + OFF_W1T);
    _Float16* W2T = (_Float16*)(ws + OFF_W2T);
    _Float16* H   = (_Float16*)(ws + OFF_H);
    int*   pair_tok = (int*)(ws + OFF_PT);
    float* pair_w   = (float*)(ws + OFF_PW);
    int*   top_idx  = (int*)(ws + OFF_TI);
    float* top_w    = (float*)(ws + OFF_TW);
    int*   counts   = (int*)(ws + OFF_CNT);
    int*   offsets  = (int*)(ws + OFF_OFS);
    int*   cursors  = (int*)(ws + OFF_CUR);

    hipMemsetAsync(counts, 0, 192, stream);                       // counts/offsets/cursors
    hipMemsetAsync(d_out, 0, (size_t)T_TOKENS * DDIM * 4, stream); // y accumulated via atomics

    router_kernel<<<T_TOKENS / 4, 256, 0, stream>>>(x, choice, xh, top_idx, top_w, counts);
    scan_kernel<<<1, 64, 0, stream>>>(counts, offsets, cursors);
    fill_kernel<<<T_TOKENS / 256, 256, 0, stream>>>(top_idx, top_w, cursors, pair_tok, pair_w);

    // W1 [E][D][F] -> W1T [E][F][D];  W2 [E][F][D] -> W2T [E][D][F]
    transpose_cvt<<<dim3(FDIM / 64, DDIM / 64, NEXP), 256, 0, stream>>>(W1, W1T, DDIM, FDIM);
    transpose_cvt<<<dim3(DDIM / 64, FDIM / 64, NEXP), 256, 0, stream>>>(W2, W2T, FDIM, DDIM);

    // GEMM1: H = silu(xh_gather @ W1[e]), M<=cnt, N=F, K=D
    moe_gemm<true, 0><<<dim3(FDIM / 128, NPAIR / 128, NEXP), 256, 0, stream>>>(
        xh, W1T, H, nullptr, pair_tok, pair_w, counts, offsets, DDIM, FDIM);
    // GEMM2: y[tok] += w * (H @ W2[e]), N=D, K=F
    moe_gemm<false, 1><<<dim3(DDIM / 128, NPAIR / 128, NEXP), 256, 0, stream>>>(
        H, W2T, nullptr, y, pair_tok, pair_w, counts, offsets, FDIM, DDIM);
}

// Round 2
// 846.141 us; speedup vs baseline: 1.4954x; 1.4954x over previous
//
#include <hip/hip_runtime.h>
#include <hip/hip_fp16.h>
#include <cmath>

// Problem constants (B=2, S=2048, D=1024, F=4096, E=8, TOP_K=2)
#define T_TOKENS 4096
#define DDIM     1024
#define FDIM     4096
#define NEXP     8
#define NPAIR    8192   // T_TOKENS * TOP_K
#define MBMAX    64     // NPAIR / 128

typedef _Float16 half8  __attribute__((ext_vector_type(8)));
typedef _Float16 half4v __attribute__((ext_vector_type(4)));
typedef float    floatx4 __attribute__((ext_vector_type(4)));

// async global->LDS, 16B per lane. Dest must be the wave-uniform chunk base:
// HW writes lane l at base + l*16 (linear). Source address is per-lane.
#define GLOAD16(g, l) __builtin_amdgcn_global_load_lds(                     \
    (const __attribute__((address_space(1))) void*)(g),                      \
    (__attribute__((address_space(3))) void*)(l), 16, 0, 0)

// ---------------- workspace layout ----------------
static const size_t OFF_XH  = 0;                                   // [T][D] f16
static const size_t SZ_XH   = (size_t)T_TOKENS * DDIM * 2;         // 8 MiB
static const size_t OFF_W1T = OFF_XH + SZ_XH;                      // [E][F][D] f16
static const size_t SZ_WT   = (size_t)NEXP * FDIM * DDIM * 2;      // 64 MiB
static const size_t OFF_W2T = OFF_W1T + SZ_WT;                     // [E][D][F] f16
static const size_t OFF_H   = OFF_W2T + SZ_WT;                     // [NPAIR][F] f16
static const size_t SZ_H    = (size_t)NPAIR * FDIM * 2;            // 64 MiB
static const size_t OFF_PT  = OFF_H + SZ_H;                        // pair_tok int
static const size_t OFF_PW  = OFF_PT + NPAIR * 4;                  // pair_w  f32
static const size_t OFF_TI  = OFF_PW + NPAIR * 4;                  // top_idx int [T][2]
static const size_t OFF_TW  = OFF_TI + NPAIR * 4;                  // top_w   f32 [T][2]
static const size_t OFF_CNT = OFF_TW + NPAIR * 4;                  // counts[8]
static const size_t OFF_OFS = OFF_CNT + 64;                        // offsets[9]
static const size_t OFF_CUR = OFF_OFS + 64;                        // cursors[8]
static const size_t WS_NEED = OFF_CUR + 64;

// ---------------- router: logits -> softmax -> top2; also emit x as f16 ----------------
__global__ __launch_bounds__(256)
void router_kernel(const float* __restrict__ x, const float* __restrict__ choice,
                   _Float16* __restrict__ xh, int* __restrict__ top_idx,
                   float* __restrict__ top_w, int* __restrict__ counts)
{
    __shared__ float ch[NEXP * DDIM];                 // 32 KiB
    for (int i = threadIdx.x * 4; i < NEXP * DDIM; i += 256 * 4) {
        *(float4*)&ch[i] = *(const float4*)&choice[i];
    }
    __syncthreads();

    const int lane = threadIdx.x & 63;
    const int wv   = threadIdx.x >> 6;
    const int t    = blockIdx.x * 4 + wv;             // one wave per token

    const float* xp = x + (size_t)t * DDIM;
    float4 xr[4];
#pragma unroll
    for (int p = 0; p < 4; ++p) xr[p] = *(const float4*)(xp + p * 256 + lane * 4);

#pragma unroll
    for (int p = 0; p < 4; ++p) {
        half4v hv = { (_Float16)xr[p].x, (_Float16)xr[p].y,
                      (_Float16)xr[p].z, (_Float16)xr[p].w };
        *(half4v*)(xh + (size_t)t * DDIM + p * 256 + lane * 4) = hv;
    }

    float lg[NEXP];
#pragma unroll
    for (int e = 0; e < NEXP; ++e) {
        float s = 0.f;
#pragma unroll
        for (int p = 0; p < 4; ++p) {
            float4 c4 = *(float4*)&ch[e * DDIM + p * 256 + lane * 4];
            s += xr[p].x * c4.x + xr[p].y * c4.y + xr[p].z * c4.z + xr[p].w * c4.w;
        }
#pragma unroll
        for (int o = 32; o; o >>= 1) s += __shfl_xor(s, o, 64);
        lg[e] = s;
    }

    if (lane == 0) {
        float mx = lg[0];
#pragma unroll
        for (int e = 1; e < NEXP; ++e) mx = fmaxf(mx, lg[e]);
        float w[NEXP]; float sum = 0.f;
#pragma unroll
        for (int e = 0; e < NEXP; ++e) { w[e] = expf(lg[e] - mx); sum += w[e]; }
        float inv = 1.f / sum;
#pragma unroll
        for (int e = 0; e < NEXP; ++e) w[e] *= inv;
        int i0 = 0; float w0 = w[0];
#pragma unroll
        for (int e = 1; e < NEXP; ++e) if (w[e] > w0) { w0 = w[e]; i0 = e; }
        int i1 = -1; float w1 = -1.f;
#pragma unroll
        for (int e = 0; e < NEXP; ++e) if (e != i0 && w[e] > w1) { w1 = w[e]; i1 = e; }
        top_idx[t * 2 + 0] = i0;  top_w[t * 2 + 0] = w0;
        top_idx[t * 2 + 1] = i1;  top_w[t * 2 + 1] = w1;
        atomicAdd(&counts[i0], 1);
        atomicAdd(&counts[i1], 1);
    }
}

__global__ void scan_kernel(const int* __restrict__ counts, int* __restrict__ offsets,
                            int* __restrict__ cursors)
{
    if (threadIdx.x == 0) {
        int o = 0;
        for (int e = 0; e < NEXP; ++e) { offsets[e] = o; cursors[e] = o; o += counts[e]; }
        offsets[NEXP] = o;
    }
}

__global__ __launch_bounds__(256)
void fill_kernel(const int* __restrict__ top_idx, const float* __restrict__ top_w,
                 int* __restrict__ cursors, int* __restrict__ pair_tok,
                 float* __restrict__ pair_w)
{
    int t = blockIdx.x * 256 + threadIdx.x;
#pragma unroll
    for (int k = 0; k < 2; ++k) {
        int e = top_idx[t * 2 + k];
        int pos = atomicAdd(&cursors[e], 1);
        pair_tok[pos] = t;
        pair_w[pos]   = top_w[t * 2 + k];
    }
}

// ---------------- transpose + f32->f16 convert: in [E][R][C] -> out [E][C][R] ----------------
__global__ __launch_bounds__(256)
void transpose_cvt(const float* __restrict__ in, _Float16* __restrict__ out, int R, int C)
{
    __shared__ float tile[64][65];
    const int e  = blockIdx.z;
    const float*    ip = in  + ((size_t)e * R + blockIdx.y * 64) * C + blockIdx.x * 64;
    _Float16*       op = out + ((size_t)e * C + blockIdx.x * 64) * R + blockIdx.y * 64;
    const int lr = threadIdx.x >> 4;          // 0..15
    const int lc = (threadIdx.x & 15) * 4;    // 0..60
#pragma unroll
    for (int p = 0; p < 4; ++p) {
        float4 v = *(const float4*)(ip + (size_t)(lr + p * 16) * C + lc);
        tile[lc + 0][lr + p * 16] = v.x;
        tile[lc + 1][lr + p * 16] = v.y;
        tile[lc + 2][lr + p * 16] = v.z;
        tile[lc + 3][lr + p * 16] = v.w;
    }
    __syncthreads();
#pragma unroll
    for (int p = 0; p < 4; ++p) {
        int oc = lr + p * 16;
        half4v hv = { (_Float16)tile[oc][lc + 0], (_Float16)tile[oc][lc + 1],
                      (_Float16)tile[oc][lc + 2], (_Float16)tile[oc][lc + 3] };
        *(half4v*)(op + (size_t)oc * R + lc) = hv;
    }
}

// ---------------- grouped GEMM (m97 structure): C[M,N] = A[M,K] * Bt[N,K]^T per expert ----
// 1D grid, bijective chunked XCD swizzle: XCD x owns logical chunk x (one expert).
// Within expert: group-m order (GM m-blocks per group, nb sweeps inside) for L2 reuse.
// BK=64, tile 128x128, 4 waves, global_load_lds 16B staging, single LDS buffer.
template<bool GATHER, int EPI, int GM>
__global__ __launch_bounds__(256)
void moe_gemm(const _Float16* __restrict__ Abase, const _Float16* __restrict__ Bt,
              _Float16* __restrict__ Hout, float* __restrict__ Yout,
              const int* __restrict__ pair_tok, const float* __restrict__ pair_w,
              const int* __restrict__ counts, const int* __restrict__ offsets,
              const int K, const int N, const int NB)
{
    const int q  = gridDim.x >> 3;                       // gridDim.x % 8 == 0
    const int wg = (blockIdx.x & 7) * q + (blockIdx.x >> 3);
    const int per_e = MBMAX * NB;
    const int e  = wg / per_e;
    int ide = wg - e * per_e;
    const int g = ide / (NB * GM);
    ide -= g * (NB * GM);
    const int nb  = ide / GM;
    const int mb  = g * GM + (ide - nb * GM);

    const int cnt = counts[e];
    if (mb * 128 >= cnt) return;
    const int off = offsets[e];

    const int tid  = threadIdx.x;
    const int lane = tid & 63;
    const int wv   = tid >> 6;
    const int wm   = wv >> 1, wn = wv & 1;

    __shared__ __align__(16) _Float16 As[128 * 64];      // 16 KiB, linear [row][64]
    __shared__ __align__(16) _Float16 Bs[128 * 64];      // 16 KiB

    // staging: wave stages 4 chunks each of A and B; chunk = 8 rows x 64 halves = 1 KiB
    const int crow = lane >> 3;          // row within chunk
    const int kofs = (lane & 7) * 8;     // halves within row

    const _Float16* asrc[4];
    const _Float16* bsrc[4];
#pragma unroll
    for (int i = 0; i < 4; ++i) {
        const int ca = wv * 4 + i;
        int r = mb * 128 + ca * 8 + crow;
        int pr = off + (r < cnt ? r : cnt - 1);
        long rowi = GATHER ? (long)pair_tok[pr] : (long)pr;
        asrc[i] = Abase + (size_t)rowi * K + kofs;
        const int n = nb * 128 + ca * 8 + crow;
        bsrc[i] = Bt + ((size_t)e * N + n) * K + kofs;
    }

    floatx4 acc[4][4] = {};
    const int kc = (lane >> 4) * 8;
    const int fr = lane & 15;
    const int nK = K >> 6;               // BK = 64

    for (int kt = 0; kt < nK; ++kt) {
        __syncthreads();
        const int ko = kt * 64;
#pragma unroll
        for (int i = 0; i < 4; ++i) {
            GLOAD16(asrc[i] + ko, &As[(wv * 4 + i) * 512]);
            GLOAD16(bsrc[i] + ko, &Bs[(wv * 4 + i) * 512]);
        }
        __syncthreads();                 // compiler drains vmcnt before barrier
#pragma unroll
        for (int s = 0; s < 2; ++s) {
            half8 af[4], bf[4];
#pragma unroll
            for (int i = 0; i < 4; ++i)
                af[i] = *(const half8*)&As[(wm * 64 + i * 16 + fr) * 64 + s * 32 + kc];
#pragma unroll
            for (int j = 0; j < 4; ++j)
                bf[j] = *(const half8*)&Bs[(wn * 64 + j * 16 + fr) * 64 + s * 32 + kc];
#pragma unroll
            for (int i = 0; i < 4; ++i)
#pragma unroll
                for (int j = 0; j < 4; ++j)
                    acc[i][j] = __builtin_amdgcn_mfma_f32_16x16x32_f16(af[i], bf[j], acc[i][j], 0, 0, 0);
        }
    }

    // epilogue: C/D layout col = lane&15, row = (lane>>4)*4 + reg  [m89-verified]
    const int qr = lane >> 4;
    const int nbase = nb * 128 + wn * 64;
#pragma unroll
    for (int i = 0; i < 4; ++i) {
#pragma unroll
        for (int r = 0; r < 4; ++r) {
            const int gm = mb * 128 + wm * 64 + i * 16 + qr * 4 + r;
            if (gm < cnt) {
                if (EPI == 0) {
                    const size_t hrow = (size_t)(off + gm) * FDIM;
#pragma unroll
                    for (int j = 0; j < 4; ++j) {
                        float v = acc[i][j][r];
                        v = v / (1.f + expf(-v));            // silu
                        Hout[hrow + nbase + j * 16 + fr] = (_Float16)v;
                    }
                } else {
                    const int pr = off + gm;
                    const int tok = pair_tok[pr];
                    const float w = pair_w[pr];
                    const size_t yrow = (size_t)tok * DDIM;
#pragma unroll
                    for (int j = 0; j < 4; ++j)
                        atomicAdd(&Yout[yrow + nbase + j * 16 + fr], w * acc[i][j][r]);
                }
            }
        }
    }
}

// ---------------- launch ----------------
extern "C" void kernel_launch(void* const* d_in, const int* in_sizes, int n_in,
                              void* d_out, int out_size, void* d_ws, size_t ws_size,
                              hipStream_t stream)
{
    const float* x      = (const float*)d_in[0];
    const float* choice = (const float*)d_in[1];
    const float* W1     = (const float*)d_in[2];
    const float* W2     = (const float*)d_in[3];
    float* y = (float*)d_out;

    char* ws = (char*)d_ws;
    if (ws_size < WS_NEED) return;   // need ~200 MiB of scratch

    _Float16* xh  = (_Float16*)(ws + OFF_XH);
    _Float16* W1T = (_Float16*)(ws + OFF_W1T);
    _Float16* W2T = (_Float16*)(ws + OFF_W2T);
    _Float16* H   = (_Float16*)(ws + OFF_H);
    int*   pair_tok = (int*)(ws + OFF_PT);
    float* pair_w   = (float*)(ws + OFF_PW);
    int*   top_idx  = (int*)(ws + OFF_TI);
    float* top_w    = (float*)(ws + OFF_TW);
    int*   counts   = (int*)(ws + OFF_CNT);
    int*   offsets  = (int*)(ws + OFF_OFS);
    int*   cursors  = (int*)(ws + OFF_CUR);

    hipMemsetAsync(counts, 0, 192, stream);                        // counts/offsets/cursors
    hipMemsetAsync(d_out, 0, (size_t)T_TOKENS * DDIM * 4, stream); // y via atomics

    router_kernel<<<T_TOKENS / 4, 256, 0, stream>>>(x, choice, xh, top_idx, top_w, counts);
    scan_kernel<<<1, 64, 0, stream>>>(counts, offsets, cursors);
    fill_kernel<<<T_TOKENS / 256, 256, 0, stream>>>(top_idx, top_w, cursors, pair_tok, pair_w);

    // W1 [E][D][F] -> W1T [E][F][D];  W2 [E][F][D] -> W2T [E][D][F]
    transpose_cvt<<<dim3(FDIM / 64, DDIM / 64, NEXP), 256, 0, stream>>>(W1, W1T, DDIM, FDIM);
    transpose_cvt<<<dim3(DDIM / 64, FDIM / 64, NEXP), 256, 0, stream>>>(W2, W2T, FDIM, DDIM);

    // GEMM1: H = silu(xh_gather @ W1[e]^T-layout), K=D, N=F.  GM=64: mb-fast within nb,
    // A panel (~2 MB/expert) stays hot in the expert's XCD L2.
    const int NB1 = FDIM / 128;
    moe_gemm<true, 0, 64><<<NEXP * MBMAX * NB1, 256, 0, stream>>>(
        xh, W1T, H, nullptr, pair_tok, pair_w, counts, offsets, DDIM, FDIM, NB1);

    // GEMM2: y[tok] += w * (H @ W2[e]), K=F, N=D.  GM=2: working set (2MB A + 1MB B-tile)
    // fits the 4 MB XCD L2.
    const int NB2 = DDIM / 128;
    moe_gemm<false, 1, 2><<<NEXP * MBMAX * NB2, 256, 0, stream>>>(
        H, W2T, nullptr, y, pair_tok, pair_w, counts, offsets, FDIM, DDIM, NB2);
}

// Round 5
// 766.287 us; speedup vs baseline: 1.6513x; 1.1042x over previous
//
#include <hip/hip_runtime.h>
#include <hip/hip_fp16.h>
#include <cmath>

// Problem constants (B=2, S=2048, D=1024, F=4096, E=8, TOP_K=2)
#define T_TOKENS 4096
#define DDIM     1024
#define FDIM     4096
#define NEXP     8
#define NPAIR    8192   // T_TOKENS * TOP_K

typedef _Float16 half8  __attribute__((ext_vector_type(8)));
typedef _Float16 half4v __attribute__((ext_vector_type(4)));
typedef float    floatx4 __attribute__((ext_vector_type(4)));

// async global->LDS, 16B per lane. Dest is the wave-uniform chunk base:
// HW writes lane l at base + l*16 (linear). Source address is per-lane.
#define GLOAD16(g, l) __builtin_amdgcn_global_load_lds(                     \
    (const __attribute__((address_space(1))) void*)(g),                      \
    (__attribute__((address_space(3))) void*)(l), 16, 0, 0)

// ---------------- workspace layout ----------------
static const size_t OFF_XH  = 0;                                   // [T][D] f16
static const size_t SZ_XH   = (size_t)T_TOKENS * DDIM * 2;         // 8 MiB
static const size_t OFF_W1T = OFF_XH + SZ_XH;                      // [E][F][D] f16 (reused as H2 f32 later)
static const size_t SZ_WT   = (size_t)NEXP * FDIM * DDIM * 2;      // 64 MiB
static const size_t OFF_W2T = OFF_W1T + SZ_WT;                     // [E][D][F] f16
static const size_t OFF_H   = OFF_W2T + SZ_WT;                     // [NPAIR][F] f16
static const size_t SZ_H    = (size_t)NPAIR * FDIM * 2;            // 64 MiB
static const size_t OFF_PT  = OFF_H + SZ_H;                        // pair_tok int
static const size_t OFF_TI  = OFF_PT + NPAIR * 4;                  // top_idx int [T][2]
static const size_t OFF_TW  = OFF_TI + NPAIR * 4;                  // top_w   f32 [T][2]
static const size_t OFF_PS  = OFF_TW + NPAIR * 4;                  // pslot  int [T][2]
static const size_t OFF_CNT = OFF_PS + NPAIR * 4;                  // counts[8]
static const size_t OFF_OFS = OFF_CNT + 64;                        // offsets[9]
static const size_t OFF_CUR = OFF_OFS + 64;                        // cursors[8]
static const size_t WS_NEED = OFF_CUR + 64;
// H2 partials [NPAIR][D] f32 = 32 MiB, aliases the (dead-by-then) W1T region.

// ---------------- router: logits -> softmax -> top2; also emit x as f16 ----------------
__global__ __launch_bounds__(256)
void router_kernel(const float* __restrict__ x, const float* __restrict__ choice,
                   _Float16* __restrict__ xh, int* __restrict__ top_idx,
                   float* __restrict__ top_w, int* __restrict__ counts)
{
    __shared__ float ch[NEXP * DDIM];                 // 32 KiB
    for (int i = threadIdx.x * 4; i < NEXP * DDIM; i += 256 * 4) {
        *(float4*)&ch[i] = *(const float4*)&choice[i];
    }
    __syncthreads();

    const int lane = threadIdx.x & 63;
    const int wv   = threadIdx.x >> 6;
    const int t    = blockIdx.x * 4 + wv;             // one wave per token

    const float* xp = x + (size_t)t * DDIM;
    float4 xr[4];
#pragma unroll
    for (int p = 0; p < 4; ++p) xr[p] = *(const float4*)(xp + p * 256 + lane * 4);

#pragma unroll
    for (int p = 0; p < 4; ++p) {
        half4v hv = { (_Float16)xr[p].x, (_Float16)xr[p].y,
                      (_Float16)xr[p].z, (_Float16)xr[p].w };
        *(half4v*)(xh + (size_t)t * DDIM + p * 256 + lane * 4) = hv;
    }

    float lg[NEXP];
#pragma unroll
    for (int e = 0; e < NEXP; ++e) {
        float s = 0.f;
#pragma unroll
        for (int p = 0; p < 4; ++p) {
            float4 c4 = *(float4*)&ch[e * DDIM + p * 256 + lane * 4];
            s += xr[p].x * c4.x + xr[p].y * c4.y + xr[p].z * c4.z + xr[p].w * c4.w;
        }
#pragma unroll
        for (int o = 32; o; o >>= 1) s += __shfl_xor(s, o, 64);
        lg[e] = s;
    }

    if (lane == 0) {
        float mx = lg[0];
#pragma unroll
        for (int e = 1; e < NEXP; ++e) mx = fmaxf(mx, lg[e]);
        float w[NEXP]; float sum = 0.f;
#pragma unroll
        for (int e = 0; e < NEXP; ++e) { w[e] = expf(lg[e] - mx); sum += w[e]; }
        float inv = 1.f / sum;
#pragma unroll
        for (int e = 0; e < NEXP; ++e) w[e] *= inv;
        int i0 = 0; float w0 = w[0];
#pragma unroll
        for (int e = 1; e < NEXP; ++e) if (w[e] > w0) { w0 = w[e]; i0 = e; }
        int i1 = -1; float w1 = -1.f;
#pragma unroll
        for (int e = 0; e < NEXP; ++e) if (e != i0 && w[e] > w1) { w1 = w[e]; i1 = e; }
        top_idx[t * 2 + 0] = i0;  top_w[t * 2 + 0] = w0;
        top_idx[t * 2 + 1] = i1;  top_w[t * 2 + 1] = w1;
        atomicAdd(&counts[i0], 1);
        atomicAdd(&counts[i1], 1);
    }
}

__global__ void scan_kernel(const int* __restrict__ counts, int* __restrict__ offsets,
                            int* __restrict__ cursors)
{
    if (threadIdx.x == 0) {
        int o = 0;
        for (int e = 0; e < NEXP; ++e) { offsets[e] = o; cursors[e] = o; o += counts[e]; }
        offsets[NEXP] = o;
    }
}

__global__ __launch_bounds__(256)
void fill_kernel(const int* __restrict__ top_idx, const float* __restrict__ top_w,
                 int* __restrict__ cursors, int* __restrict__ pair_tok,
                 int* __restrict__ pslot)
{
    int t = blockIdx.x * 256 + threadIdx.x;
#pragma unroll
    for (int k = 0; k < 2; ++k) {
        int e = top_idx[t * 2 + k];
        int pos = atomicAdd(&cursors[e], 1);
        pair_tok[pos] = t;
        pslot[t * 2 + k] = pos;
    }
}

// ---------------- transpose + f32->f16 convert: in [E][R][C] -> out [E][C][R] ----------------
__global__ __launch_bounds__(256)
void transpose_cvt(const float* __restrict__ in, _Float16* __restrict__ out, int R, int C)
{
    __shared__ float tile[64][65];
    const int e  = blockIdx.z;
    const float*    ip = in  + ((size_t)e * R + blockIdx.y * 64) * C + blockIdx.x * 64;
    _Float16*       op = out + ((size_t)e * C + blockIdx.x * 64) * R + blockIdx.y * 64;
    const int lr = threadIdx.x >> 4;          // 0..15
    const int lc = (threadIdx.x & 15) * 4;    // 0..60
#pragma unroll
    for (int p = 0; p < 4; ++p) {
        float4 v = *(const float4*)(ip + (size_t)(lr + p * 16) * C + lc);
        tile[lc + 0][lr + p * 16] = v.x;
        tile[lc + 1][lr + p * 16] = v.y;
        tile[lc + 2][lr + p * 16] = v.z;
        tile[lc + 3][lr + p * 16] = v.w;
    }
    __syncthreads();
#pragma unroll
    for (int p = 0; p < 4; ++p) {
        int oc = lr + p * 16;
        half4v hv = { (_Float16)tile[oc][lc + 0], (_Float16)tile[oc][lc + 1],
                      (_Float16)tile[oc][lc + 2], (_Float16)tile[oc][lc + 3] };
        *(half4v*)(op + (size_t)oc * R + lc) = hv;
    }
}

// ---------------- grouped GEMM, 2-phase double-buffered (T3 minimum recipe) ----------------
// C[M,N] = A[M,K] * Bt[N,K]^T per expert. 128x128 tile, BK=64, 4 waves.
// LDS linear dest for global_load_lds; bank-conflict fix via pre-swizzled global
// source col + XOR on read col (rule #21: both sides, same involution).
// EPI 0: silu -> Hout f16 [pair][F].  EPI 1: plain f32 -> H2out [pair][N].
template<bool GATHER, int EPI, int GM, int NB>
__global__ __launch_bounds__(256)
void moe_gemm(const _Float16* __restrict__ Abase, const _Float16* __restrict__ Bt,
              _Float16* __restrict__ Hout, float* __restrict__ H2out,
              const int* __restrict__ pair_tok,
              const int* __restrict__ counts, const int* __restrict__ offsets,
              const int K, const int N)
{
    const int MBSTR = 16;
    const int q  = gridDim.x >> 3;                       // gridDim.x % 8 == 0
    const int wg = (blockIdx.x & 7) * q + (blockIdx.x >> 3);
    const int per_e = MBSTR * NB;
    const int e  = wg / per_e;
    int ide = wg - e * per_e;
    const int g = ide / (NB * GM);
    ide -= g * (NB * GM);
    const int nb  = ide / GM;
    const int mb0 = g * GM + (ide - nb * GM);

    const int cnt = counts[e];
    const int off = offsets[e];

    const int tid  = threadIdx.x;
    const int lane = tid & 63;
    const int wv   = tid >> 6;
    const int wm   = wv >> 1, wn = wv & 1;

    __shared__ __align__(16) _Float16 As[2][128 * 64];   // 2 x 16 KiB
    __shared__ __align__(16) _Float16 Bs[2][128 * 64];   // 2 x 16 KiB

    // staging: chunk = 8 rows x 128 B; wave stages 4 chunks of A and 4 of B.
    const int crow = lane >> 3;                          // row within chunk = row & 7
    const int swz  = ((lane & 7) * 8) ^ (crow << 3);     // pre-swizzled source col (halves)

    const int kc = (lane >> 4) * 8;
    const int fr = lane & 15;
    const int rsw = (fr & 7) << 3;                       // read-side XOR (halves)
    const int nK = K >> 6;                               // BK = 64

    // B source pointers are mb-independent
    const _Float16* bsrc[4];
#pragma unroll
    for (int i = 0; i < 4; ++i) {
        const int n = nb * 128 + (wv * 4 + i) * 8 + crow;
        bsrc[i] = Bt + ((size_t)e * N + n) * K + swz;
    }

    for (int mb = mb0; mb * 128 < cnt; mb += MBSTR) {
        const _Float16* asrc[4];
#pragma unroll
        for (int i = 0; i < 4; ++i) {
            int r = mb * 128 + (wv * 4 + i) * 8 + crow;
            int pr = off + (r < cnt ? r : cnt - 1);
            long rowi = GATHER ? (long)pair_tok[pr] : (long)pr;
            asrc[i] = Abase + (size_t)rowi * K + swz;
        }

        floatx4 acc[4][4] = {};

        // prologue: fill buffer 0
#pragma unroll
        for (int i = 0; i < 4; ++i) {
            GLOAD16(asrc[i], &As[0][(wv * 4 + i) * 512]);
            GLOAD16(bsrc[i], &Bs[0][(wv * 4 + i) * 512]);
        }
        __syncthreads();                                 // drains vmcnt(0) first

        int cur = 0;
        for (int kt = 0; kt < nK; ++kt) {
            if (kt + 1 < nK) {                           // issue next tile BEFORE compute
                const int ko = (kt + 1) * 64;
#pragma unroll
                for (int i = 0; i < 4; ++i) {
                    GLOAD16(asrc[i] + ko, &As[cur ^ 1][(wv * 4 + i) * 512]);
                    GLOAD16(bsrc[i] + ko, &Bs[cur ^ 1][(wv * 4 + i) * 512]);
                }
            }
#pragma unroll
            for (int s = 0; s < 2; ++s) {
                const int rc = (s * 32 + kc) ^ rsw;      // swizzled read col
                half8 af[4], bf[4];
#pragma unroll
                for (int i = 0; i < 4; ++i)
                    af[i] = *(const half8*)&As[cur][(wm * 64 + i * 16 + fr) * 64 + rc];
#pragma unroll
                for (int j = 0; j < 4; ++j)
                    bf[j] = *(const half8*)&Bs[cur][(wn * 64 + j * 16 + fr) * 64 + rc];
#pragma unroll
                for (int i = 0; i < 4; ++i)
#pragma unroll
                    for (int j = 0; j < 4; ++j)
                        acc[i][j] = __builtin_amdgcn_mfma_f32_16x16x32_f16(af[i], bf[j], acc[i][j], 0, 0, 0);
            }
            __syncthreads();                             // one barrier per K-tile
            cur ^= 1;
        }

        // epilogue: C/D layout col = lane&15, row = (lane>>4)*4 + reg  [m89-verified]
        const int qr = lane >> 4;
        const int nbase = nb * 128 + wn * 64;
#pragma unroll
        for (int i = 0; i < 4; ++i) {
#pragma unroll
            for (int r = 0; r < 4; ++r) {
                const int gm = mb * 128 + wm * 64 + i * 16 + qr * 4 + r;
                if (gm < cnt) {
                    if (EPI == 0) {
                        const size_t hrow = (size_t)(off + gm) * FDIM;
#pragma unroll
                        for (int j = 0; j < 4; ++j) {
                            float v = acc[i][j][r];
                            v = v / (1.f + expf(-v));            // silu
                            Hout[hrow + nbase + j * 16 + fr] = (_Float16)v;
                        }
                    } else {
                        const size_t hrow = (size_t)(off + gm) * DDIM;
#pragma unroll
                        for (int j = 0; j < 4; ++j)
                            H2out[hrow + nbase + j * 16 + fr] = acc[i][j][r];
                    }
                }
            }
        }
    }
}

// ---------------- combine: y[t] = w0*H2[p0] + w1*H2[p1] ----------------
__global__ __launch_bounds__(256)
void combine_kernel(const float* __restrict__ H2, const int* __restrict__ pslot,
                    const float* __restrict__ top_w, float* __restrict__ y)
{
    const int t  = blockIdx.x;
    const int p0 = pslot[t * 2 + 0], p1 = pslot[t * 2 + 1];
    const float w0 = top_w[t * 2 + 0], w1 = top_w[t * 2 + 1];
    const int d = threadIdx.x * 4;
    float4 a = *(const float4*)&H2[(size_t)p0 * DDIM + d];
    float4 b = *(const float4*)&H2[(size_t)p1 * DDIM + d];
    float4 o = { w0 * a.x + w1 * b.x, w0 * a.y + w1 * b.y,
                 w0 * a.z + w1 * b.z, w0 * a.w + w1 * b.w };
    *(float4*)&y[(size_t)t * DDIM + d] = o;
}

// ---------------- launch ----------------
extern "C" void kernel_launch(void* const* d_in, const int* in_sizes, int n_in,
                              void* d_out, int out_size, void* d_ws, size_t ws_size,
                              hipStream_t stream)
{
    const float* x      = (const float*)d_in[0];
    const float* choice = (const float*)d_in[1];
    const float* W1     = (const float*)d_in[2];
    const float* W2     = (const float*)d_in[3];
    float* y = (float*)d_out;

    char* ws = (char*)d_ws;
    if (ws_size < WS_NEED) return;   // need ~200 MiB of scratch

    _Float16* xh  = (_Float16*)(ws + OFF_XH);
    _Float16* W1T = (_Float16*)(ws + OFF_W1T);
    _Float16* W2T = (_Float16*)(ws + OFF_W2T);
    _Float16* H   = (_Float16*)(ws + OFF_H);
    float*    H2  = (float*)(ws + OFF_W1T);   // aliases W1T (dead after GEMM1)
    int*   pair_tok = (int*)(ws + OFF_PT);
    int*   top_idx  = (int*)(ws + OFF_TI);
    float* top_w    = (float*)(ws + OFF_TW);
    int*   pslot    = (int*)(ws + OFF_PS);
    int*   counts   = (int*)(ws + OFF_CNT);
    int*   offsets  = (int*)(ws + OFF_OFS);
    int*   cursors  = (int*)(ws + OFF_CUR);

    hipMemsetAsync(counts, 0, 192, stream);   // counts/offsets/cursors

    router_kernel<<<T_TOKENS / 4, 256, 0, stream>>>(x, choice, xh, top_idx, top_w, counts);
    scan_kernel<<<1, 64, 0, stream>>>(counts, offsets, cursors);
    fill_kernel<<<T_TOKENS / 256, 256, 0, stream>>>(top_idx, top_w, cursors, pair_tok, pslot);

    // W1 [E][D][F] -> W1T [E][F][D];  W2 [E][F][D] -> W2T [E][D][F]
    transpose_cvt<<<dim3(FDIM / 64, DDIM / 64, NEXP), 256, 0, stream>>>(W1, W1T, DDIM, FDIM);
    transpose_cvt<<<dim3(DDIM / 64, FDIM / 64, NEXP), 256, 0, stream>>>(W2, W2T, FDIM, DDIM);

    // GEMM1: H = silu(xh_gather @ W1[e]), K=D, N=F. GM=16: nb-major, full A panel
    // (~2 MB/expert) stays L2-hot, B streamed once (~10 MB/expert fetch).
    moe_gemm<true, 0, 16, FDIM / 128><<<NEXP * 16 * (FDIM / 128), 256, 0, stream>>>(
        xh, W1T, H, nullptr, pair_tok, counts, offsets, DDIM, FDIM);

    // GEMM2: H2[pair] = H @ W2[e], K=F, N=D. GM=2: 2-mb groups (~2 MB A hot) x nb sweep.
    moe_gemm<false, 1, 2, DDIM / 128><<<NEXP * 16 * (DDIM / 128), 256, 0, stream>>>(
        H, W2T, nullptr, H2, pair_tok, counts, offsets, FDIM, DDIM);

    // y[t] = w0*H2[p0] + w1*H2[p1]  (dense write, no atomics, no d_out memset)
    combine_kernel<<<T_TOKENS, 256, 0, stream>>>(H2, pslot, top_w, y);
}

// Round 7
// 760.555 us; speedup vs baseline: 1.6637x; 1.0075x over previous
//
#include <hip/hip_runtime.h>
#include <hip/hip_fp16.h>
#include <cmath>

// Problem constants (B=2, S=2048, D=1024, F=4096, E=8, TOP_K=2)
#define T_TOKENS 4096
#define DDIM     1024
#define FDIM     4096
#define NEXP     8
#define NPAIR    8192   // T_TOKENS * TOP_K

typedef _Float16 half8  __attribute__((ext_vector_type(8)));
typedef _Float16 half4v __attribute__((ext_vector_type(4)));
typedef float    floatx4 __attribute__((ext_vector_type(4)));

// async global->LDS, 16B per lane. Dest is the wave-uniform chunk base:
// HW writes lane l at base + l*16 (linear). Source address is per-lane.
#define GLOAD16(g, l) __builtin_amdgcn_global_load_lds(                     \
    (const __attribute__((address_space(1))) void*)(g),                      \
    (__attribute__((address_space(3))) void*)(l), 16, 0, 0)

// ---------------- workspace layout ----------------
static const size_t OFF_XH  = 0;                                   // [T][D] f16
static const size_t SZ_XH   = (size_t)T_TOKENS * DDIM * 2;         // 8 MiB
static const size_t OFF_W1T = OFF_XH + SZ_XH;                      // [E][F][D] f16 (reused as H2 f32 later)
static const size_t SZ_WT   = (size_t)NEXP * FDIM * DDIM * 2;      // 64 MiB
static const size_t OFF_W2T = OFF_W1T + SZ_WT;                     // [E][D][F] f16
static const size_t OFF_H   = OFF_W2T + SZ_WT;                     // [NPAIR][F] f16
static const size_t SZ_H    = (size_t)NPAIR * FDIM * 2;            // 64 MiB
static const size_t OFF_PT  = OFF_H + SZ_H;                        // pair_tok int
static const size_t OFF_TI  = OFF_PT + NPAIR * 4;                  // top_idx int [T][2]
static const size_t OFF_TW  = OFF_TI + NPAIR * 4;                  // top_w   f32 [T][2]
static const size_t OFF_PS  = OFF_TW + NPAIR * 4;                  // pslot  int [T][2]
static const size_t OFF_CNT = OFF_PS + NPAIR * 4;                  // counts[8]
static const size_t OFF_OFS = OFF_CNT + 64;                        // offsets[9]
static const size_t OFF_CUR = OFF_OFS + 64;                        // cursors[8]
static const size_t WS_NEED = OFF_CUR + 64;
// H2 partials [2][NPAIR][D] f32 = 64 MiB, aliases the (dead-by-then) W1T region.

// ---------------- router: logits -> softmax -> top2; also emit x as f16 ----------------
__global__ __launch_bounds__(256)
void router_kernel(const float* __restrict__ x, const float* __restrict__ choice,
                   _Float16* __restrict__ xh, int* __restrict__ top_idx,
                   float* __restrict__ top_w, int* __restrict__ counts)
{
    __shared__ float ch[NEXP * DDIM];                 // 32 KiB
    for (int i = threadIdx.x * 4; i < NEXP * DDIM; i += 256 * 4) {
        *(float4*)&ch[i] = *(const float4*)&choice[i];
    }
    __syncthreads();

    const int lane = threadIdx.x & 63;
    const int wv   = threadIdx.x >> 6;
    const int t    = blockIdx.x * 4 + wv;             // one wave per token

    const float* xp = x + (size_t)t * DDIM;
    float4 xr[4];
#pragma unroll
    for (int p = 0; p < 4; ++p) xr[p] = *(const float4*)(xp + p * 256 + lane * 4);

#pragma unroll
    for (int p = 0; p < 4; ++p) {
        half4v hv = { (_Float16)xr[p].x, (_Float16)xr[p].y,
                      (_Float16)xr[p].z, (_Float16)xr[p].w };
        *(half4v*)(xh + (size_t)t * DDIM + p * 256 + lane * 4) = hv;
    }

    float lg[NEXP];
#pragma unroll
    for (int e = 0; e < NEXP; ++e) {
        float s = 0.f;
#pragma unroll
        for (int p = 0; p < 4; ++p) {
            float4 c4 = *(float4*)&ch[e * DDIM + p * 256 + lane * 4];
            s += xr[p].x * c4.x + xr[p].y * c4.y + xr[p].z * c4.z + xr[p].w * c4.w;
        }
#pragma unroll
        for (int o = 32; o; o >>= 1) s += __shfl_xor(s, o, 64);
        lg[e] = s;
    }

    if (lane == 0) {
        float mx = lg[0];
#pragma unroll
        for (int e = 1; e < NEXP; ++e) mx = fmaxf(mx, lg[e]);
        float w[NEXP]; float sum = 0.f;
#pragma unroll
        for (int e = 0; e < NEXP; ++e) { w[e] = expf(lg[e] - mx); sum += w[e]; }
        float inv = 1.f / sum;
#pragma unroll
        for (int e = 0; e < NEXP; ++e) w[e] *= inv;
        int i0 = 0; float w0 = w[0];
#pragma unroll
        for (int e = 1; e < NEXP; ++e) if (w[e] > w0) { w0 = w[e]; i0 = e; }
        int i1 = -1; float w1 = -1.f;
#pragma unroll
        for (int e = 0; e < NEXP; ++e) if (e != i0 && w[e] > w1) { w1 = w[e]; i1 = e; }
        top_idx[t * 2 + 0] = i0;  top_w[t * 2 + 0] = w0;
        top_idx[t * 2 + 1] = i1;  top_w[t * 2 + 1] = w1;
        atomicAdd(&counts[i0], 1);
        atomicAdd(&counts[i1], 1);
    }
}

__global__ void scan_kernel(const int* __restrict__ counts, int* __restrict__ offsets,
                            int* __restrict__ cursors)
{
    if (threadIdx.x == 0) {
        int o = 0;
        for (int e = 0; e < NEXP; ++e) { offsets[e] = o; cursors[e] = o; o += counts[e]; }
        offsets[NEXP] = o;
    }
}

__global__ __launch_bounds__(256)
void fill_kernel(const int* __restrict__ top_idx, const float* __restrict__ top_w,
                 int* __restrict__ cursors, int* __restrict__ pair_tok,
                 int* __restrict__ pslot)
{
    int t = blockIdx.x * 256 + threadIdx.x;
#pragma unroll
    for (int k = 0; k < 2; ++k) {
        int e = top_idx[t * 2 + k];
        int pos = atomicAdd(&cursors[e], 1);
        pair_tok[pos] = t;
        pslot[t * 2 + k] = pos;
    }
}

// ---------------- transpose + f32->f16 convert: in [E][R][C] -> out [E][C][R] ----------------
__global__ __launch_bounds__(256)
void transpose_cvt(const float* __restrict__ in, _Float16* __restrict__ out, int R, int C)
{
    __shared__ float tile[64][65];
    const int e  = blockIdx.z;
    const float*    ip = in  + ((size_t)e * R + blockIdx.y * 64) * C + blockIdx.x * 64;
    _Float16*       op = out + ((size_t)e * C + blockIdx.x * 64) * R + blockIdx.y * 64;
    const int lr = threadIdx.x >> 4;          // 0..15
    const int lc = (threadIdx.x & 15) * 4;    // 0..60
#pragma unroll
    for (int p = 0; p < 4; ++p) {
        float4 v = *(const float4*)(ip + (size_t)(lr + p * 16) * C + lc);
        tile[lc + 0][lr + p * 16] = v.x;
        tile[lc + 1][lr + p * 16] = v.y;
        tile[lc + 2][lr + p * 16] = v.z;
        tile[lc + 3][lr + p * 16] = v.w;
    }
    __syncthreads();
#pragma unroll
    for (int p = 0; p < 4; ++p) {
        int oc = lr + p * 16;
        half4v hv = { (_Float16)tile[oc][lc + 0], (_Float16)tile[oc][lc + 1],
                      (_Float16)tile[oc][lc + 2], (_Float16)tile[oc][lc + 3] };
        *(half4v*)(op + (size_t)oc * R + lc) = hv;
    }
}

// ---------------- grouped GEMM, 256x256 tile, 2-phase double-buffered ----------------
// C[M,N] = A[M,K_slice] * Bt[N,K_slice]^T per expert (K split into NKS slices).
// 8 waves (512 thr), wave grid 2Mx4N, per-wave 128x64 output -> 64 MFMA per K-tile
// per wave (2x the 128^2 structure's compute per barrier; m230: 682 TF at 2ph).
// Bank-conflict-free via paired XOR involution (verified: 0 conflicts in R5).
// EPI 0: silu -> Hout f16 [pair][F].  EPI 1: f32 -> H2out [ks][pair][DDIM].
template<bool GATHER, int EPI, int NB, int NKS>
__global__ __launch_bounds__(512, 1)
void moe_gemm256(const _Float16* __restrict__ Abase, const _Float16* __restrict__ Bt,
                 _Float16* __restrict__ Hout, float* __restrict__ H2out,
                 const int* __restrict__ pair_tok,
                 const int* __restrict__ counts, const int* __restrict__ offsets,
                 const int Kfull, const int N)
{
    // grid = NEXP * 4slots * NB * NKS (%8==0). XCD swizzle: chunk c -> XCD c;
    // per-expert tile count == grid/8 -> exactly one expert per XCD.
    const int q  = gridDim.x >> 3;
    const int wg = (blockIdx.x & 7) * q + (blockIdx.x >> 3);
    const int per_e = 4 * NB * NKS;
    const int e  = wg / per_e;
    int ide = wg - e * per_e;
    const int nb   = ide / (4 * NKS);            // nb-major
    int rem  = ide - nb * (4 * NKS);
    const int ks   = rem >> 2;
    const int slot = rem & 3;                    // mb fastest -> A panel L2-hot

    const int cnt = counts[e];
    const int off = offsets[e];

    const int tid  = threadIdx.x;
    const int lane = tid & 63;
    const int wv   = tid >> 6;                   // 0..7
    const int wm   = wv >> 2, wn = wv & 3;       // 2 x 4 wave grid

    __shared__ __align__(16) _Float16 As[2][256 * 64];   // 2 x 32 KiB
    __shared__ __align__(16) _Float16 Bs[2][256 * 64];   // 2 x 32 KiB

    // staging: chunk = 8 rows x 128 B; wave stages 4 chunks of A and 4 of B.
    const int crow = lane >> 3;                          // row within chunk
    const int swz  = ((lane & 7) * 8) ^ (crow << 3);     // pre-swizzled source col (halves)

    const int kc = (lane >> 4) * 8;
    const int fr = lane & 15;
    const int rsw = (fr & 7) << 3;                       // read-side XOR (same involution)

    const int Kloc = Kfull / NKS;
    const int k0   = ks * Kloc;
    const int nK   = Kloc >> 6;                          // BK = 64

    const _Float16* bsrc[4];
#pragma unroll
    for (int i = 0; i < 4; ++i) {
        const int n = nb * 256 + (wv * 4 + i) * 8 + crow;
        bsrc[i] = Bt + ((size_t)e * N + n) * Kfull + k0 + swz;
    }

    for (int mb = slot; mb * 256 < cnt; mb += 4) {
        const _Float16* asrc[4];
#pragma unroll
        for (int i = 0; i < 4; ++i) {
            int r = mb * 256 + (wv * 4 + i) * 8 + crow;
            int pr = off + (r < cnt ? r : cnt - 1);
            long rowi = GATHER ? (long)pair_tok[pr] : (long)pr;
            asrc[i] = Abase + (size_t)rowi * Kfull + k0 + swz;
        }

        floatx4 acc[8][4] = {};

        // prologue: fill buffer 0
#pragma unroll
        for (int i = 0; i < 4; ++i) {
            GLOAD16(asrc[i], &As[0][(wv * 4 + i) * 512]);
            GLOAD16(bsrc[i], &Bs[0][(wv * 4 + i) * 512]);
        }
        __syncthreads();                                 // drains vmcnt(0) first

        int cur = 0;
        for (int kt = 0; kt < nK; ++kt) {
            if (kt + 1 < nK) {                           // issue next tile BEFORE compute
                const int ko = (kt + 1) * 64;
#pragma unroll
                for (int i = 0; i < 4; ++i) {
                    GLOAD16(asrc[i] + ko, &As[cur ^ 1][(wv * 4 + i) * 512]);
                    GLOAD16(bsrc[i] + ko, &Bs[cur ^ 1][(wv * 4 + i) * 512]);
                }
            }
#pragma unroll
            for (int s = 0; s < 2; ++s) {
                const int rc = (s * 32 + kc) ^ rsw;      // swizzled read col
                half8 af[8], bf[4];
#pragma unroll
                for (int i = 0; i < 8; ++i)
                    af[i] = *(const half8*)&As[cur][(wm * 128 + i * 16 + fr) * 64 + rc];
#pragma unroll
                for (int j = 0; j < 4; ++j)
                    bf[j] = *(const half8*)&Bs[cur][(wn * 64 + j * 16 + fr) * 64 + rc];
#pragma unroll
                for (int i = 0; i < 8; ++i)
#pragma unroll
                    for (int j = 0; j < 4; ++j)
                        acc[i][j] = __builtin_amdgcn_mfma_f32_16x16x32_f16(af[i], bf[j], acc[i][j], 0, 0, 0);
            }
            __syncthreads();                             // one barrier per K-tile
            cur ^= 1;
        }

        // epilogue: C/D layout col = lane&15, row = (lane>>4)*4 + reg  [m89-verified]
        const int qr = lane >> 4;
        const int nbase = nb * 256 + wn * 64;
#pragma unroll
        for (int i = 0; i < 8; ++i) {
#pragma unroll
            for (int r = 0; r < 4; ++r) {
                const int gm = mb * 256 + wm * 128 + i * 16 + qr * 4 + r;
                if (gm < cnt) {
                    if (EPI == 0) {
                        const size_t hrow = (size_t)(off + gm) * FDIM;
#pragma unroll
                        for (int j = 0; j < 4; ++j) {
                            float v = acc[i][j][r];
                            v = v / (1.f + expf(-v));            // silu
                            Hout[hrow + nbase + j * 16 + fr] = (_Float16)v;
                        }
                    } else {
                        const size_t hrow = ((size_t)ks * NPAIR + off + gm) * DDIM;
#pragma unroll
                        for (int j = 0; j < 4; ++j)
                            H2out[hrow + nbase + j * 16 + fr] = acc[i][j][r];
                    }
                }
            }
        }
    }
}

// ---------------- combine: y[t] = w0*(H2[0][p0]+H2[1][p0]) + w1*(...p1) ----------------
__global__ __launch_bounds__(256)
void combine_kernel(const float* __restrict__ H2, const int* __restrict__ pslot,
                    const float* __restrict__ top_w, float* __restrict__ y)
{
    const int t  = blockIdx.x;
    const int p0 = pslot[t * 2 + 0], p1 = pslot[t * 2 + 1];
    const float w0 = top_w[t * 2 + 0], w1 = top_w[t * 2 + 1];
    const int d = threadIdx.x * 4;
    float4 a0 = *(const float4*)&H2[(size_t)p0 * DDIM + d];
    float4 a1 = *(const float4*)&H2[((size_t)NPAIR + p0) * DDIM + d];
    float4 b0 = *(const float4*)&H2[(size_t)p1 * DDIM + d];
    float4 b1 = *(const float4*)&H2[((size_t)NPAIR + p1) * DDIM + d];
    float4 o = { w0 * (a0.x + a1.x) + w1 * (b0.x + b1.x),
                 w0 * (a0.y + a1.y) + w1 * (b0.y + b1.y),
                 w0 * (a0.z + a1.z) + w1 * (b0.z + b1.z),
                 w0 * (a0.w + a1.w) + w1 * (b0.w + b1.w) };
    *(float4*)&y[(size_t)t * DDIM + d] = o;
}

// ---------------- launch ----------------
extern "C" void kernel_launch(void* const* d_in, const int* in_sizes, int n_in,
                              void* d_out, int out_size, void* d_ws, size_t ws_size,
                              hipStream_t stream)
{
    const float* x      = (const float*)d_in[0];
    const float* choice = (const float*)d_in[1];
    const float* W1     = (const float*)d_in[2];
    const float* W2     = (const float*)d_in[3];
    float* y = (float*)d_out;

    char* ws = (char*)d_ws;
    if (ws_size < WS_NEED) return;   // need ~200 MiB of scratch

    _Float16* xh  = (_Float16*)(ws + OFF_XH);
    _Float16* W1T = (_Float16*)(ws + OFF_W1T);
    _Float16* W2T = (_Float16*)(ws + OFF_W2T);
    _Float16* H   = (_Float16*)(ws + OFF_H);
    float*    H2  = (float*)(ws + OFF_W1T);   // [2][NPAIR][D] f32, aliases W1T (dead after GEMM1)
    int*   pair_tok = (int*)(ws + OFF_PT);
    int*   top_idx  = (int*)(ws + OFF_TI);
    float* top_w    = (float*)(ws + OFF_TW);
    int*   pslot    = (int*)(ws + OFF_PS);
    int*   counts   = (int*)(ws + OFF_CNT);
    int*   offsets  = (int*)(ws + OFF_OFS);
    int*   cursors  = (int*)(ws + OFF_CUR);

    hipMemsetAsync(counts, 0, 192, stream);   // counts/offsets/cursors

    router_kernel<<<T_TOKENS / 4, 256, 0, stream>>>(x, choice, xh, top_idx, top_w, counts);
    scan_kernel<<<1, 64, 0, stream>>>(counts, offsets, cursors);
    fill_kernel<<<T_TOKENS / 256, 256, 0, stream>>>(top_idx, top_w, cursors, pair_tok, pslot);

    // W1 [E][D][F] -> W1T [E][F][D];  W2 [E][F][D] -> W2T [E][D][F]
    transpose_cvt<<<dim3(FDIM / 64, DDIM / 64, NEXP), 256, 0, stream>>>(W1, W1T, DDIM, FDIM);
    transpose_cvt<<<dim3(DDIM / 64, FDIM / 64, NEXP), 256, 0, stream>>>(W2, W2T, FDIM, DDIM);

    // GEMM1: H = silu(xh_gather @ W1[e]), K=1024, N=4096. Grid 8e x 4slots x 16nb = 512,
    // one expert per XCD; mb-fast -> gathered A panel (~2 MB) L2-hot, B streamed once.
    moe_gemm256<true, 0, FDIM / 256, 1><<<NEXP * 4 * (FDIM / 256), 512, 0, stream>>>(
        xh, W1T, H, nullptr, pair_tok, counts, offsets, DDIM, FDIM);

    // GEMM2: H2[ks] = H @ W2[e][ks-slice], K=4096 split x2, N=1024.
    // Grid 8e x 4slots x 4nb x 2ks = 256 -> full GPU at 1 block/CU.
    moe_gemm256<false, 1, DDIM / 256, 2><<<NEXP * 4 * (DDIM / 256) * 2, 512, 0, stream>>>(
        H, W2T, nullptr, H2, pair_tok, counts, offsets, FDIM, DDIM);

    // y[t] = w0*(H2[0][p0]+H2[1][p0]) + w1*(H2[0][p1]+H2[1][p1])
    combine_kernel<<<T_TOKENS, 256, 0, stream>>>(H2, pslot, top_w, y);
}